// Round 7
// baseline (613.855 us; speedup 1.0000x reference)
//
#include <hip/hip_runtime.h>
#include <hip/hip_bf16.h>

// GDGCN: out[b,c,m,t] = sum_n softmax_row(relu(t1 nv2^T))[n,m] * x[b,c,n,t]
// t1 = nv1 @ (sum_d tv[d] k[d,:,:]);  N=8192, D=32, cols = B*C*T = 192.
// R7: ONE persistent cooperative kernel (512 blocks x 512 thr, 2/CU
// co-resident) running all 5 phases with device-scope grid barriers —
// eliminates ~6 sequential dispatch gaps + small-kernel launch tails that
// made up ~108 of 180 µs in R6. Phase bodies are R6 ports (mega unchanged).
// Fallback to the R6 multi-kernel path if cooperative launch is unavailable.

#define NN 8192
#define DD 32
#define TT 12
#define NSPLIT 8
#define CHUNK 1024
#define ESTR 72  // LDS row stride (ushort): b64-write 4/bank, b128-read 8/bank = data min
#define NBLK 512

typedef __attribute__((ext_vector_type(8))) short bf16x8;
typedef __attribute__((ext_vector_type(4))) short bf16x4;
typedef __attribute__((ext_vector_type(4))) float f32x4;

static __device__ __forceinline__ unsigned short f2bf(float f) {
  unsigned int u = __float_as_uint(f);
  u = (u + 0x7FFFu + ((u >> 16) & 1u)) >> 16;  // RNE bf16
  return (unsigned short)u;
}

static __device__ __forceinline__ float fexp2(float x) {
#if __has_builtin(__builtin_amdgcn_exp2f)
  return __builtin_amdgcn_exp2f(x);
#else
  return __builtin_exp2f(x);
#endif
}

// device-scope sense-reversal grid barrier (all NBLK blocks co-resident)
static __device__ __forceinline__ void gridsync(int* bar) {
  __syncthreads();
  if (threadIdx.x == 0) {
    __threadfence();  // agent-scope release of this block's prior writes
    int gen = __hip_atomic_load(&bar[1], __ATOMIC_RELAXED, __HIP_MEMORY_SCOPE_AGENT);
    int arr = __hip_atomic_fetch_add(&bar[0], 1, __ATOMIC_ACQ_REL, __HIP_MEMORY_SCOPE_AGENT);
    if (arr == NBLK - 1) {
      __hip_atomic_store(&bar[0], 0, __ATOMIC_RELAXED, __HIP_MEMORY_SCOPE_AGENT);
      __hip_atomic_fetch_add(&bar[1], 1, __ATOMIC_RELEASE, __HIP_MEMORY_SCOPE_AGENT);
    } else {
      while (__hip_atomic_load(&bar[1], __ATOMIC_ACQUIRE, __HIP_MEMORY_SCOPE_AGENT) == gen)
        __builtin_amdgcn_s_sleep(1);
    }
    __threadfence();  // agent-scope acquire before reading others' data
  }
  __syncthreads();
}

__global__ __launch_bounds__(512, 4) void k_all(
    const float* __restrict__ x, const float* __restrict__ nv1,
    const float* __restrict__ nv2, const float* __restrict__ timevec,
    const float* __restrict__ kk, const int* __restrict__ tind,
    unsigned short* __restrict__ t1b, unsigned short* __restrict__ nv2b,
    float* __restrict__ sums, unsigned short* __restrict__ yT,
    float* __restrict__ part, float* __restrict__ out, int* __restrict__ bar) {
  __shared__ __align__(16) unsigned char smem[2 * 128 * ESTR * 2];  // 36864 B, reused per phase
  const int tid = threadIdx.x;
  const int b = blockIdx.x;
  const int w = tid >> 6, lane = tid & 63, q = lane >> 4, i16 = lane & 15;
  const f32x4 z4 = {0.f, 0.f, 0.f, 0.f};

  // ---------------- phase 1: prep (blocks 0..63) + zero sums (all) ----------
  if (tid < 16) sums[b * 16 + tid] = 0.f;
  if (b < 64) {
    float* cs = (float*)smem;
    const float* tv = timevec + (size_t)tind[0] * DD;
    for (int idx = tid; idx < 1024; idx += 512) {
      float acc = 0.f;
#pragma unroll
      for (int d = 0; d < DD; ++d) acc += tv[d] * kk[d * 1024 + idx];
      cs[idx] = acc;
    }
    __syncthreads();
    const int nbase = b * 128;
    const int f = tid & 31, sub = tid >> 5;
#pragma unroll 4
    for (int it = 0; it < 8; ++it) {
      const int n = nbase + it * 16 + sub;
      const float* nr = nv1 + (size_t)n * DD;
      float acc = 0.f;
#pragma unroll
      for (int e = 0; e < DD; ++e) acc += nr[e] * cs[e * DD + f];
      t1b[(size_t)n * DD + f] = f2bf(acc * 1.4426950408889634f);  // fold log2(e)
    }
#pragma unroll 4
    for (int it = 0; it < 8; ++it) {
      const int idx = nbase * DD + it * 512 + tid;
      nv2b[idx] = f2bf(nv2[idx]);
    }
  }
  gridsync(bar);

  // ---------------- phase 2: stats — sums[n] += sum_m exp2(relu(.)) ---------
  {
    const int nbase = (b & 127) * 64 + (w & 3) * 16;
    const int m0 = (b >> 7) * 2048 + (w >> 2) * 1024;
    bf16x8 a = *(const bf16x8*)(t1b + (size_t)(nbase + i16) * DD + q * 8);
    float s[4] = {0.f, 0.f, 0.f, 0.f};
    for (int mt = m0; mt < m0 + 1024; mt += 64) {
#pragma unroll
      for (int u = 0; u < 4; ++u) {
        bf16x8 bb = *(const bf16x8*)(nv2b + (size_t)(mt + u * 16 + i16) * DD + q * 8);
        f32x4 d = __builtin_amdgcn_mfma_f32_16x16x32_bf16(a, bb, z4, 0, 0, 0);
#pragma unroll
        for (int r = 0; r < 4; ++r) s[r] += fexp2(fmaxf(d[r], 0.f));
      }
    }
#pragma unroll
    for (int r = 0; r < 4; ++r)
      for (int off = 1; off < 16; off <<= 1) s[r] += __shfl_xor(s[r], off, 64);
    if (i16 == 0) {
#pragma unroll
      for (int r = 0; r < 4; ++r) atomicAdd(&sums[nbase + q * 4 + r], s[r]);
    }
  }
  gridsync(bar);

  // ---------------- phase 3: yT[col][n] = bf16(x / sums) --------------------
  {
    float* xs = (float*)smem;          // 3072 floats
    float* rs = (float*)smem + 3072;   // 256 floats
    const int n0 = (b & 31) * 256;
    const int bc = b >> 5;
    const float* xp = x + (size_t)bc * NN * TT + (size_t)n0 * TT;
#pragma unroll
    for (int j = 0; j < 6; ++j) xs[j * 512 + tid] = xp[j * 512 + tid];
    if (tid < 256) rs[tid] = 1.0f / sums[n0 + tid];
    __syncthreads();
#pragma unroll
    for (int j = 0; j < 6; ++j) {
      const int idx = j * 512 + tid;
      const int t = idx >> 8, i = idx & 255;
      yT[(size_t)(bc * TT + t) * NN + n0 + i] = f2bf(xs[i * TT + t] * rs[i]);
    }
  }
  gridsync(bar);

  // ---------------- phase 4: mega GEMM into part ----------------------------
  {
    typedef unsigned short EwRow[ESTR];
    EwRow* Ew0 = (EwRow*)smem;          // [128][ESTR]
    EwRow* Ew1 = (EwRow*)smem + 128;    // [128][ESTR]
    const int wc = w >> 1, wm = w & 1;
    const int mb = (b >> 3) * 128;
    const int nt0 = (b & 7) * CHUNK;

    const bf16x8 bg = *(const bf16x8*)(nv2b + (size_t)(mb + w * 16 + i16) * DD + q * 8);

    f32x4 acc[3][4];
#pragma unroll
    for (int c = 0; c < 3; ++c)
#pragma unroll
      for (int ms = 0; ms < 4; ++ms) acc[c][ms] = (f32x4){0.f, 0.f, 0.f, 0.f};

    // prologue: stage 0 into Ew0
#pragma unroll
    for (int s = 0; s < 4; ++s) {
      bf16x8 at = *(const bf16x8*)(t1b + (size_t)(nt0 + s * 16 + i16) * DD + q * 8);
      f32x4 d = __builtin_amdgcn_mfma_f32_16x16x32_bf16(at, bg, z4, 0, 0, 0);
      bf16x4 e;
#pragma unroll
      for (int r = 0; r < 4; ++r) e[r] = (short)f2bf(fexp2(fmaxf(d[r], 0.f)));
      *(bf16x4*)&Ew0[w * 16 + i16][s * 16 + q * 4] = e;
    }
    __syncthreads();

    for (int st = 0; st < 16; ++st) {
      EwRow* Ecur = (st & 1) ? Ew1 : Ew0;
      EwRow* Enxt = (st & 1) ? Ew0 : Ew1;
      const int nt = nt0 + st * 64;
      const bool more = (st < 15);

      bf16x8 atn[4];
      if (more) {
#pragma unroll
        for (int s = 0; s < 4; ++s)
          atn[s] = *(const bf16x8*)(t1b + (size_t)(nt + 64 + s * 16 + i16) * DD + q * 8);
      }

      bf16x8 yfr[3], efr[4];
#pragma unroll
      for (int c = 0; c < 3; ++c)
        yfr[c] = *(const bf16x8*)(yT + (size_t)((wc * 3 + c) * 16 + i16) * NN + nt + q * 8);
#pragma unroll
      for (int ms = 0; ms < 4; ++ms)
        efr[ms] = *(const bf16x8*)&Ecur[wm * 64 + ms * 16 + i16][q * 8];

      f32x4 d0, d1;
      if (more) {
        d0 = __builtin_amdgcn_mfma_f32_16x16x32_bf16(atn[0], bg, z4, 0, 0, 0);
        d1 = __builtin_amdgcn_mfma_f32_16x16x32_bf16(atn[1], bg, z4, 0, 0, 0);
      }

#pragma unroll
      for (int c = 0; c < 3; ++c)
#pragma unroll
        for (int ms = 0; ms < 4; ++ms)
          acc[c][ms] = __builtin_amdgcn_mfma_f32_16x16x32_bf16(yfr[c], efr[ms], acc[c][ms], 0, 0, 0);

      if (more) {
        bf16x4 e0, e1;
#pragma unroll
        for (int r = 0; r < 4; ++r) {
          e0[r] = (short)f2bf(fexp2(fmaxf(d0[r], 0.f)));
          e1[r] = (short)f2bf(fexp2(fmaxf(d1[r], 0.f)));
        }
        *(bf16x4*)&Enxt[w * 16 + i16][q * 4] = e0;
        *(bf16x4*)&Enxt[w * 16 + i16][16 + q * 4] = e1;
        f32x4 d2 = __builtin_amdgcn_mfma_f32_16x16x32_bf16(atn[2], bg, z4, 0, 0, 0);
        f32x4 d3 = __builtin_amdgcn_mfma_f32_16x16x32_bf16(atn[3], bg, z4, 0, 0, 0);
        bf16x4 e2, e3;
#pragma unroll
        for (int r = 0; r < 4; ++r) {
          e2[r] = (short)f2bf(fexp2(fmaxf(d2[r], 0.f)));
          e3[r] = (short)f2bf(fexp2(fmaxf(d3[r], 0.f)));
        }
        *(bf16x4*)&Enxt[w * 16 + i16][32 + q * 4] = e2;
        *(bf16x4*)&Enxt[w * 16 + i16][48 + q * 4] = e3;
      }

#pragma unroll
      for (int c = 0; c < 3; ++c)
        yfr[c] = *(const bf16x8*)(yT + (size_t)((wc * 3 + c) * 16 + i16) * NN + nt + 32 + q * 8);
#pragma unroll
      for (int ms = 0; ms < 4; ++ms)
        efr[ms] = *(const bf16x8*)&Ecur[wm * 64 + ms * 16 + i16][32 + q * 8];
#pragma unroll
      for (int c = 0; c < 3; ++c)
#pragma unroll
        for (int ms = 0; ms < 4; ++ms)
          acc[c][ms] = __builtin_amdgcn_mfma_f32_16x16x32_bf16(yfr[c], efr[ms], acc[c][ms], 0, 0, 0);

      __syncthreads();
    }

    float* pp = part + (size_t)(b & 7) * 192 * NN;
#pragma unroll
    for (int c = 0; c < 3; ++c)
#pragma unroll
      for (int ms = 0; ms < 4; ++ms) {
        const int colbase = (wc * 3 + c) * 16 + q * 4;
        const int m = mb + wm * 64 + ms * 16 + i16;
#pragma unroll
        for (int r = 0; r < 4; ++r)
          pp[(size_t)(colbase + r) * NN + m] = acc[c][ms][r];
      }
  }
  gridsync(bar);

  // ---------------- phase 5: reduce partials -> out[bc][m][t] ---------------
  {
    float* os = (float*)smem;  // 3072 floats
    const int m0 = (b & 31) * 256;
    const int bc = b >> 5;
    const int ml = tid & 255, th = tid >> 8;
#pragma unroll
    for (int t = th * 6; t < th * 6 + 6; ++t) {
      const int col = bc * TT + t;
      float s = 0.f;
#pragma unroll
      for (int nc = 0; nc < NSPLIT; ++nc)
        s += part[((size_t)nc * 192 + col) * NN + m0 + ml];
      os[ml * TT + t] = s;
    }
    __syncthreads();
    float* op = out + (size_t)bc * NN * TT + (size_t)m0 * TT;
#pragma unroll
    for (int j = 0; j < 6; ++j) op[j * 512 + tid] = os[j * 512 + tid];
  }
}

// ======================= fallback: R6 multi-kernel path ======================
__global__ __launch_bounds__(256) void k_prep(const float* __restrict__ nv1,
                                              const float* __restrict__ nv2,
                                              const float* __restrict__ timevec,
                                              const float* __restrict__ kk,
                                              const int* __restrict__ tind,
                                              unsigned short* __restrict__ t1b,
                                              unsigned short* __restrict__ nv2b) {
  __shared__ float cs[1024];
  const int tid = threadIdx.x;
  const float* tv = timevec + (size_t)tind[0] * DD;
  for (int idx = tid; idx < 1024; idx += 256) {
    float acc = 0.f;
#pragma unroll
    for (int d = 0; d < DD; ++d) acc += tv[d] * kk[d * 1024 + idx];
    cs[idx] = acc;
  }
  __syncthreads();
  const int nbase = blockIdx.x * 128;
  const int f = tid & 31, sub = tid >> 5;
#pragma unroll 4
  for (int it = 0; it < 16; ++it) {
    const int n = nbase + it * 8 + sub;
    const float* nr = nv1 + (size_t)n * DD;
    float acc = 0.f;
#pragma unroll
    for (int e = 0; e < DD; ++e) acc += nr[e] * cs[e * DD + f];
    t1b[(size_t)n * DD + f] = f2bf(acc * 1.4426950408889634f);
  }
#pragma unroll 4
  for (int it = 0; it < 16; ++it) {
    const int idx = nbase * DD + it * 256 + tid;
    nv2b[idx] = f2bf(nv2[idx]);
  }
}

__global__ __launch_bounds__(256) void k_stats(const unsigned short* __restrict__ t1b,
                                               const unsigned short* __restrict__ nv2b,
                                               float* __restrict__ sums) {
  const int tid = threadIdx.x;
  const int w = tid >> 6, lane = tid & 63, q = lane >> 4, i16 = lane & 15;
  const int nbase = blockIdx.x * 64 + w * 16;
  bf16x8 a = *(const bf16x8*)(t1b + (size_t)(nbase + i16) * DD + q * 8);
  const f32x4 z4 = {0.f, 0.f, 0.f, 0.f};
  float s[4] = {0.f, 0.f, 0.f, 0.f};
  const int m0 = blockIdx.y * 1024;
  for (int mt = m0; mt < m0 + 1024; mt += 64) {
#pragma unroll
    for (int u = 0; u < 4; ++u) {
      bf16x8 b = *(const bf16x8*)(nv2b + (size_t)(mt + u * 16 + i16) * DD + q * 8);
      f32x4 d = __builtin_amdgcn_mfma_f32_16x16x32_bf16(a, b, z4, 0, 0, 0);
#pragma unroll
      for (int r = 0; r < 4; ++r) s[r] += fexp2(fmaxf(d[r], 0.f));
    }
  }
#pragma unroll
  for (int r = 0; r < 4; ++r)
    for (int off = 1; off < 16; off <<= 1) s[r] += __shfl_xor(s[r], off, 64);
  if (i16 == 0) {
#pragma unroll
    for (int r = 0; r < 4; ++r) atomicAdd(&sums[nbase + q * 4 + r], s[r]);
  }
}

__global__ __launch_bounds__(256) void k_y(const float* __restrict__ x,
                                           const float* __restrict__ sums,
                                           unsigned short* __restrict__ yT) {
  __shared__ float xs[3072];
  const int tid = threadIdx.x;
  const int n0 = blockIdx.x * 256;
  const int bc = blockIdx.y;
  const float* xp = x + (size_t)bc * NN * TT + (size_t)n0 * TT;
#pragma unroll
  for (int j = 0; j < 12; ++j) xs[j * 256 + tid] = xp[j * 256 + tid];
  __syncthreads();
  const float rinv = 1.0f / sums[n0 + tid];
#pragma unroll
  for (int t = 0; t < 12; ++t)
    yT[(size_t)(bc * TT + t) * NN + n0 + tid] = f2bf(xs[tid * 12 + t] * rinv);
}

__global__ __launch_bounds__(512, 4) void k_mega(const unsigned short* __restrict__ t1b,
                                                 const unsigned short* __restrict__ nv2b,
                                                 const unsigned short* __restrict__ yT,
                                                 float* __restrict__ part) {
  const int tid = threadIdx.x;
  const int w = tid >> 6, lane = tid & 63, q = lane >> 4, i16 = lane & 15;
  const int wc = w >> 1, wm = w & 1;
  const int mb = blockIdx.x * 128;
  const int nt0 = blockIdx.y * CHUNK;
  __shared__ unsigned short Ew[2][128][ESTR];
  const bf16x8 bg = *(const bf16x8*)(nv2b + (size_t)(mb + w * 16 + i16) * DD + q * 8);
  const f32x4 z4 = {0.f, 0.f, 0.f, 0.f};
  f32x4 acc[3][4];
#pragma unroll
  for (int c = 0; c < 3; ++c)
#pragma unroll
    for (int ms = 0; ms < 4; ++ms) acc[c][ms] = (f32x4){0.f, 0.f, 0.f, 0.f};
#pragma unroll
  for (int s = 0; s < 4; ++s) {
    bf16x8 at = *(const bf16x8*)(t1b + (size_t)(nt0 + s * 16 + i16) * DD + q * 8);
    f32x4 d = __builtin_amdgcn_mfma_f32_16x16x32_bf16(at, bg, z4, 0, 0, 0);
    bf16x4 e;
#pragma unroll
    for (int r = 0; r < 4; ++r) e[r] = (short)f2bf(fexp2(fmaxf(d[r], 0.f)));
    *(bf16x4*)&Ew[0][w * 16 + i16][s * 16 + q * 4] = e;
  }
  __syncthreads();
  int p = 0;
  for (int st = 0; st < 16; ++st, p ^= 1) {
    const int nt = nt0 + st * 64;
    const bool more = (st < 15);
    bf16x8 atn[4];
    if (more) {
#pragma unroll
      for (int s = 0; s < 4; ++s)
        atn[s] = *(const bf16x8*)(t1b + (size_t)(nt + 64 + s * 16 + i16) * DD + q * 8);
    }
    bf16x8 yfr[3], efr[4];
#pragma unroll
    for (int c = 0; c < 3; ++c)
      yfr[c] = *(const bf16x8*)(yT + (size_t)((wc * 3 + c) * 16 + i16) * NN + nt + q * 8);
#pragma unroll
    for (int ms = 0; ms < 4; ++ms)
      efr[ms] = *(const bf16x8*)&Ew[p][wm * 64 + ms * 16 + i16][q * 8];
    f32x4 d0, d1;
    if (more) {
      d0 = __builtin_amdgcn_mfma_f32_16x16x32_bf16(atn[0], bg, z4, 0, 0, 0);
      d1 = __builtin_amdgcn_mfma_f32_16x16x32_bf16(atn[1], bg, z4, 0, 0, 0);
    }
#pragma unroll
    for (int c = 0; c < 3; ++c)
#pragma unroll
      for (int ms = 0; ms < 4; ++ms)
        acc[c][ms] = __builtin_amdgcn_mfma_f32_16x16x32_bf16(yfr[c], efr[ms], acc[c][ms], 0, 0, 0);
    if (more) {
      bf16x4 e0, e1;
#pragma unroll
      for (int r = 0; r < 4; ++r) {
        e0[r] = (short)f2bf(fexp2(fmaxf(d0[r], 0.f)));
        e1[r] = (short)f2bf(fexp2(fmaxf(d1[r], 0.f)));
      }
      *(bf16x4*)&Ew[p ^ 1][w * 16 + i16][q * 4] = e0;
      *(bf16x4*)&Ew[p ^ 1][w * 16 + i16][16 + q * 4] = e1;
      f32x4 d2 = __builtin_amdgcn_mfma_f32_16x16x32_bf16(atn[2], bg, z4, 0, 0, 0);
      f32x4 d3 = __builtin_amdgcn_mfma_f32_16x16x32_bf16(atn[3], bg, z4, 0, 0, 0);
      bf16x4 e2, e3;
#pragma unroll
      for (int r = 0; r < 4; ++r) {
        e2[r] = (short)f2bf(fexp2(fmaxf(d2[r], 0.f)));
        e3[r] = (short)f2bf(fexp2(fmaxf(d3[r], 0.f)));
      }
      *(bf16x4*)&Ew[p ^ 1][w * 16 + i16][32 + q * 4] = e2;
      *(bf16x4*)&Ew[p ^ 1][w * 16 + i16][48 + q * 4] = e3;
    }
#pragma unroll
    for (int c = 0; c < 3; ++c)
      yfr[c] = *(const bf16x8*)(yT + (size_t)((wc * 3 + c) * 16 + i16) * NN + nt + 32 + q * 8);
#pragma unroll
    for (int ms = 0; ms < 4; ++ms)
      efr[ms] = *(const bf16x8*)&Ew[p][wm * 64 + ms * 16 + i16][32 + q * 8];
#pragma unroll
    for (int c = 0; c < 3; ++c)
#pragma unroll
      for (int ms = 0; ms < 4; ++ms)
        acc[c][ms] = __builtin_amdgcn_mfma_f32_16x16x32_bf16(yfr[c], efr[ms], acc[c][ms], 0, 0, 0);
    __syncthreads();
  }
  float* pp = part + (size_t)blockIdx.y * 192 * NN;
#pragma unroll
  for (int c = 0; c < 3; ++c)
#pragma unroll
    for (int ms = 0; ms < 4; ++ms) {
      const int colbase = (wc * 3 + c) * 16 + q * 4;
      const int m = mb + wm * 64 + ms * 16 + i16;
#pragma unroll
      for (int r = 0; r < 4; ++r)
        pp[(size_t)(colbase + r) * NN + m] = acc[c][ms][r];
    }
}

__global__ __launch_bounds__(256) void k_reduce(const float* __restrict__ part,
                                                float* __restrict__ out) {
  __shared__ float os[3072];
  const int tid = threadIdx.x;
  const int m0 = blockIdx.x * 256;
  const int bc = blockIdx.y;
#pragma unroll
  for (int t = 0; t < 12; ++t) {
    const int col = bc * TT + t;
    float s = 0.f;
#pragma unroll
    for (int nc = 0; nc < NSPLIT; ++nc)
      s += part[((size_t)nc * 192 + col) * NN + m0 + tid];
    os[tid * 12 + t] = s;
  }
  __syncthreads();
  float* op = out + (size_t)bc * NN * TT + (size_t)m0 * TT;
#pragma unroll
  for (int j = 0; j < 12; ++j) op[j * 256 + tid] = os[j * 256 + tid];
}

extern "C" void kernel_launch(void* const* d_in, const int* in_sizes, int n_in,
                              void* d_out, int out_size, void* d_ws, size_t ws_size,
                              hipStream_t stream) {
  const float* x = (const float*)d_in[0];
  const float* nv1 = (const float*)d_in[1];
  const float* nv2 = (const float*)d_in[2];
  const float* tv = (const float*)d_in[3];
  const float* kk = (const float*)d_in[4];
  const int* tind = (const int*)d_in[5];
  float* out = (float*)d_out;

  char* ws = (char*)d_ws;
  unsigned short* t1b  = (unsigned short*)(ws);            //  524288 B
  unsigned short* nv2b = (unsigned short*)(ws + 524288);   //  524288 B
  float* sums          = (float*)(ws + 1048576);           //   32768 B
  unsigned short* yT   = (unsigned short*)(ws + 1081344);  // 3145728 B -> 4227072
  float* part          = (float*)(ws + 4227072);           // 50331648 B -> 54558720
  int* bar             = (int*)(ws + 54558720);            //      64 B

  hipMemsetAsync(bar, 0, 64, stream);

  void* args[] = {(void*)&x,    (void*)&nv1, (void*)&nv2,  (void*)&tv,
                  (void*)&kk,   (void*)&tind, (void*)&t1b, (void*)&nv2b,
                  (void*)&sums, (void*)&yT,   (void*)&part, (void*)&out,
                  (void*)&bar};
  hipError_t e = hipLaunchCooperativeKernel((const void*)k_all, dim3(NBLK),
                                            dim3(512), args, 0, stream);
  if (e != hipSuccess) {
    (void)hipGetLastError();  // clear error state
    hipMemsetAsync(sums, 0, NN * sizeof(float), stream);
    k_prep<<<64, 256, 0, stream>>>(nv1, nv2, tv, kk, tind, t1b, nv2b);
    k_stats<<<dim3(128, 8), 256, 0, stream>>>(t1b, nv2b, sums);
    k_y<<<dim3(32, 16), 256, 0, stream>>>(x, sums, yT);
    k_mega<<<dim3(64, NSPLIT), 512, 0, stream>>>(t1b, nv2b, yT, part);
    k_reduce<<<dim3(32, 16), 256, 0, stream>>>(part, out);
  }
}

// Round 8
// 180.761 us; speedup vs baseline: 3.3959x; 3.3959x over previous
//
#include <hip/hip_runtime.h>
#include <hip/hip_bf16.h>

// GDGCN: out[b,c,m,t] = sum_n softmax_row(relu(t1 nv2^T))[n,m] * x[b,c,n,t]
// t1 = nv1 @ (sum_d tv[d] k[d,:,:]);  N=8192, D=32, cols = B*C*T = 192.
// R8: back to multi-kernel (R7 coop grid-sync cost ~400 µs — refuted).
// k_mega: stage 128n (8 barriers/chunk, was 16), XOR-swizzled 64 KB LDS
// E-dbuf (data-min bank slots for b64 writes AND b128 reads), y-q0
// prefetched across the barrier. sums zeroing folded into k_prep.

#define NN 8192
#define DD 32
#define TT 12
#define NSPLIT 8
#define CHUNK 1024

typedef __attribute__((ext_vector_type(8))) short bf16x8;
typedef __attribute__((ext_vector_type(4))) short bf16x4;
typedef __attribute__((ext_vector_type(4))) float f32x4;

static __device__ __forceinline__ unsigned short f2bf(float f) {
  unsigned int u = __float_as_uint(f);
  u = (u + 0x7FFFu + ((u >> 16) & 1u)) >> 16;  // RNE bf16
  return (unsigned short)u;
}

static __device__ __forceinline__ float fexp2(float x) {
#if __has_builtin(__builtin_amdgcn_exp2f)
  return __builtin_amdgcn_exp2f(x);
#else
  return __builtin_exp2f(x);
#endif
}

// ---- fused: core = tv.k ; t1 = (nv1@core)*log2e (bf16) ; nv2 -> bf16 ; sums=0
__global__ __launch_bounds__(256) void k_prep(const float* __restrict__ nv1,
                                              const float* __restrict__ nv2,
                                              const float* __restrict__ timevec,
                                              const float* __restrict__ kk,
                                              const int* __restrict__ tind,
                                              unsigned short* __restrict__ t1b,
                                              unsigned short* __restrict__ nv2b,
                                              float* __restrict__ sums) {
  __shared__ float cs[1024];
  const int tid = threadIdx.x;
  if (tid < 128) sums[blockIdx.x * 128 + tid] = 0.f;
  const float* tv = timevec + (size_t)tind[0] * DD;
  for (int idx = tid; idx < 1024; idx += 256) {
    float acc = 0.f;
#pragma unroll
    for (int d = 0; d < DD; ++d) acc += tv[d] * kk[d * 1024 + idx];
    cs[idx] = acc;
  }
  __syncthreads();
  const int nbase = blockIdx.x * 128;
  const int f = tid & 31, sub = tid >> 5;
#pragma unroll 4
  for (int it = 0; it < 16; ++it) {
    const int n = nbase + it * 8 + sub;
    const float* nr = nv1 + (size_t)n * DD;
    float acc = 0.f;
#pragma unroll
    for (int e = 0; e < DD; ++e) acc += nr[e] * cs[e * DD + f];
    t1b[(size_t)n * DD + f] = f2bf(acc * 1.4426950408889634f);  // fold log2(e)
  }
#pragma unroll 4
  for (int it = 0; it < 16; ++it) {
    const int idx = nbase * DD + it * 256 + tid;
    nv2b[idx] = f2bf(nv2[idx]);
  }
}

// ---- sums[n] += sum_m exp2(relu(t1[n].nv2[m]))  grid (128 n, 8 m-chunks) ----
__global__ __launch_bounds__(256) void k_stats(const unsigned short* __restrict__ t1b,
                                               const unsigned short* __restrict__ nv2b,
                                               float* __restrict__ sums) {
  const int tid = threadIdx.x;
  const int w = tid >> 6, lane = tid & 63, q = lane >> 4, i16 = lane & 15;
  const int nbase = blockIdx.x * 64 + w * 16;
  bf16x8 a = *(const bf16x8*)(t1b + (size_t)(nbase + i16) * DD + q * 8);
  const f32x4 z4 = {0.f, 0.f, 0.f, 0.f};
  float s[4] = {0.f, 0.f, 0.f, 0.f};
  const int m0 = blockIdx.y * 1024;
  for (int mt = m0; mt < m0 + 1024; mt += 64) {
#pragma unroll
    for (int u = 0; u < 4; ++u) {
      bf16x8 b = *(const bf16x8*)(nv2b + (size_t)(mt + u * 16 + i16) * DD + q * 8);
      f32x4 d = __builtin_amdgcn_mfma_f32_16x16x32_bf16(a, b, z4, 0, 0, 0);
#pragma unroll
      for (int r = 0; r < 4; ++r) s[r] += fexp2(fmaxf(d[r], 0.f));
    }
  }
#pragma unroll
  for (int r = 0; r < 4; ++r)
    for (int off = 1; off < 16; off <<= 1) s[r] += __shfl_xor(s[r], off, 64);
  if (i16 == 0) {
#pragma unroll
    for (int r = 0; r < 4; ++r) atomicAdd(&sums[nbase + q * 4 + r], s[r]);
  }
}

// ---- yT[col][n] = bf16(x[bc][n][t] / sums[n]) via LDS transpose ----
__global__ __launch_bounds__(256) void k_y(const float* __restrict__ x,
                                           const float* __restrict__ sums,
                                           unsigned short* __restrict__ yT) {
  __shared__ float xs[3072];
  const int tid = threadIdx.x;
  const int n0 = blockIdx.x * 256;
  const int bc = blockIdx.y;
  const float* xp = x + (size_t)bc * NN * TT + (size_t)n0 * TT;
#pragma unroll
  for (int j = 0; j < 12; ++j) xs[j * 256 + tid] = xp[j * 256 + tid];
  __syncthreads();
  const float rinv = 1.0f / sums[n0 + tid];
#pragma unroll
  for (int t = 0; t < 12; ++t)
    yT[(size_t)(bc * TT + t) * NN + n0 + tid] = f2bf(xs[tid * 12 + t] * rinv);
}

// ---- k_mega: part[nc][col][m] = sum_{n in chunk} E[n][m] * y[col][n] ----
// grid (64 m-blocks of 128, 8 chunks of 1024 n); 512 threads = 8 waves.
// Stage = 128 n. Gen: wave w -> E row block [w*16,w*16+16) x 128 n, in 4
// groups of 32 n (2 MFMAs + 8 exp2/lane + 2 swizzled b64 writes each),
// interleaved with the 4 acc quarters. Acc: wave (wc=w>>1, wm=w&1):
// 3 coltiles x 4 m-subs, 12 MFMAs/quarter. One barrier per 128-n stage.
// LDS: 2 x 128 x 128 bf16 = 65536 B, col XOR-swizzle (m&7)<<3 => data-min
// bank slots for both b64 writes (4) and b128 reads (8).
#define SWC(c) ((c) ^ swz)
__global__ __launch_bounds__(512, 4) void k_mega(const unsigned short* __restrict__ t1b,
                                                 const unsigned short* __restrict__ nv2b,
                                                 const unsigned short* __restrict__ yT,
                                                 float* __restrict__ part) {
  const int tid = threadIdx.x;
  const int w = tid >> 6, lane = tid & 63, q = lane >> 4, i16 = lane & 15;
  const int wc = w >> 1, wm = w & 1;
  const int mb = blockIdx.x * 128;
  const int nt0 = blockIdx.y * CHUNK;
  const int swz = (i16 & 7) << 3;

  __shared__ unsigned short Ew[2][128][128];  // 65536 B

  // gen B-frag (loop-invariant): B[d][m=i16] = nv2[mb + w*16 + i16][d]
  const bf16x8 bg = *(const bf16x8*)(nv2b + (size_t)(mb + w * 16 + i16) * DD + q * 8);
  const int rowm = w * 16 + i16;

  const f32x4 z4 = {0.f, 0.f, 0.f, 0.f};
  f32x4 acc[3][4];
#pragma unroll
  for (int c = 0; c < 3; ++c)
#pragma unroll
    for (int ms = 0; ms < 4; ++ms) acc[c][ms] = (f32x4){0.f, 0.f, 0.f, 0.f};

  // y row pointers for this wave's 3 coltiles
  const unsigned short* yp[3];
#pragma unroll
  for (int c = 0; c < 3; ++c)
    yp[c] = yT + (size_t)((wc * 3 + c) * 16 + i16) * NN + q * 8;

  // ---- prologue: generate stage 0 (128 n) into buf 0 ----
#pragma unroll
  for (int g = 0; g < 4; ++g) {
    bf16x8 a0 = *(const bf16x8*)(t1b + (size_t)(nt0 + g * 32 + i16) * DD + q * 8);
    bf16x8 a1 = *(const bf16x8*)(t1b + (size_t)(nt0 + g * 32 + 16 + i16) * DD + q * 8);
    f32x4 d0 = __builtin_amdgcn_mfma_f32_16x16x32_bf16(a0, bg, z4, 0, 0, 0);
    f32x4 d1 = __builtin_amdgcn_mfma_f32_16x16x32_bf16(a1, bg, z4, 0, 0, 0);
    bf16x4 e0, e1;
#pragma unroll
    for (int r = 0; r < 4; ++r) {
      e0[r] = (short)f2bf(fexp2(fmaxf(d0[r], 0.f)));
      e1[r] = (short)f2bf(fexp2(fmaxf(d1[r], 0.f)));
    }
    *(bf16x4*)&Ew[0][rowm][SWC(g * 32 + q * 4)] = e0;
    *(bf16x4*)&Ew[0][rowm][SWC(g * 32 + 16 + q * 4)] = e1;
  }
  // prefetch stage-0 q0 y-frags
  bf16x8 y0[3];
#pragma unroll
  for (int c = 0; c < 3; ++c) y0[c] = *(const bf16x8*)(yp[c] + nt0);
  __syncthreads();

  for (int st = 0; st < 8; ++st) {
    const int p = st & 1;
    const int nt = nt0 + st * 128;
    const bool more = (st < 7);
    const unsigned short(*Ec)[128] = Ew[p];
    unsigned short(*En)[128] = Ew[p ^ 1];

    // next-stage t1 A-frags (8 b128), issued at stage top for latency
    bf16x8 at[8];
    if (more) {
#pragma unroll
      for (int s = 0; s < 8; ++s)
        at[s] = *(const bf16x8*)(t1b + (size_t)(nt + 128 + s * 16 + i16) * DD + q * 8);
    }

    bf16x8 efr[4], y1[3], y2[3], y3[3];
    // ---- quarter 0 ----
#pragma unroll
    for (int ms = 0; ms < 4; ++ms)
      efr[ms] = *(const bf16x8*)&Ec[wm * 64 + ms * 16 + i16][SWC(q * 8)];
#pragma unroll
    for (int c = 0; c < 3; ++c) y1[c] = *(const bf16x8*)(yp[c] + nt + 32);
#pragma unroll
    for (int c = 0; c < 3; ++c)
#pragma unroll
      for (int ms = 0; ms < 4; ++ms)
        acc[c][ms] = __builtin_amdgcn_mfma_f32_16x16x32_bf16(y0[c], efr[ms], acc[c][ms], 0, 0, 0);
    if (more) {  // gen group 0 -> cols 0..31 of En
      f32x4 d0 = __builtin_amdgcn_mfma_f32_16x16x32_bf16(at[0], bg, z4, 0, 0, 0);
      f32x4 d1 = __builtin_amdgcn_mfma_f32_16x16x32_bf16(at[1], bg, z4, 0, 0, 0);
      bf16x4 e0, e1;
#pragma unroll
      for (int r = 0; r < 4; ++r) {
        e0[r] = (short)f2bf(fexp2(fmaxf(d0[r], 0.f)));
        e1[r] = (short)f2bf(fexp2(fmaxf(d1[r], 0.f)));
      }
      *(bf16x4*)&En[rowm][SWC(q * 4)] = e0;
      *(bf16x4*)&En[rowm][SWC(16 + q * 4)] = e1;
    }
    // ---- quarter 1 ----
#pragma unroll
    for (int ms = 0; ms < 4; ++ms)
      efr[ms] = *(const bf16x8*)&Ec[wm * 64 + ms * 16 + i16][SWC(32 + q * 8)];
#pragma unroll
    for (int c = 0; c < 3; ++c) y2[c] = *(const bf16x8*)(yp[c] + nt + 64);
#pragma unroll
    for (int c = 0; c < 3; ++c)
#pragma unroll
      for (int ms = 0; ms < 4; ++ms)
        acc[c][ms] = __builtin_amdgcn_mfma_f32_16x16x32_bf16(y1[c], efr[ms], acc[c][ms], 0, 0, 0);
    if (more) {  // gen group 1 -> cols 32..63
      f32x4 d0 = __builtin_amdgcn_mfma_f32_16x16x32_bf16(at[2], bg, z4, 0, 0, 0);
      f32x4 d1 = __builtin_amdgcn_mfma_f32_16x16x32_bf16(at[3], bg, z4, 0, 0, 0);
      bf16x4 e0, e1;
#pragma unroll
      for (int r = 0; r < 4; ++r) {
        e0[r] = (short)f2bf(fexp2(fmaxf(d0[r], 0.f)));
        e1[r] = (short)f2bf(fexp2(fmaxf(d1[r], 0.f)));
      }
      *(bf16x4*)&En[rowm][SWC(32 + q * 4)] = e0;
      *(bf16x4*)&En[rowm][SWC(48 + q * 4)] = e1;
    }
    // ---- quarter 2 ----
#pragma unroll
    for (int ms = 0; ms < 4; ++ms)
      efr[ms] = *(const bf16x8*)&Ec[wm * 64 + ms * 16 + i16][SWC(64 + q * 8)];
#pragma unroll
    for (int c = 0; c < 3; ++c) y3[c] = *(const bf16x8*)(yp[c] + nt + 96);
#pragma unroll
    for (int c = 0; c < 3; ++c)
#pragma unroll
      for (int ms = 0; ms < 4; ++ms)
        acc[c][ms] = __builtin_amdgcn_mfma_f32_16x16x32_bf16(y2[c], efr[ms], acc[c][ms], 0, 0, 0);
    if (more) {  // gen group 2 -> cols 64..95
      f32x4 d0 = __builtin_amdgcn_mfma_f32_16x16x32_bf16(at[4], bg, z4, 0, 0, 0);
      f32x4 d1 = __builtin_amdgcn_mfma_f32_16x16x32_bf16(at[5], bg, z4, 0, 0, 0);
      bf16x4 e0, e1;
#pragma unroll
      for (int r = 0; r < 4; ++r) {
        e0[r] = (short)f2bf(fexp2(fmaxf(d0[r], 0.f)));
        e1[r] = (short)f2bf(fexp2(fmaxf(d1[r], 0.f)));
      }
      *(bf16x4*)&En[rowm][SWC(64 + q * 4)] = e0;
      *(bf16x4*)&En[rowm][SWC(80 + q * 4)] = e1;
    }
    // ---- quarter 3 ----
#pragma unroll
    for (int ms = 0; ms < 4; ++ms)
      efr[ms] = *(const bf16x8*)&Ec[wm * 64 + ms * 16 + i16][SWC(96 + q * 8)];
    if (more) {
#pragma unroll
      for (int c = 0; c < 3; ++c) y0[c] = *(const bf16x8*)(yp[c] + nt + 128);  // next-stage q0
    }
#pragma unroll
    for (int c = 0; c < 3; ++c)
#pragma unroll
      for (int ms = 0; ms < 4; ++ms)
        acc[c][ms] = __builtin_amdgcn_mfma_f32_16x16x32_bf16(y3[c], efr[ms], acc[c][ms], 0, 0, 0);
    if (more) {  // gen group 3 -> cols 96..127
      f32x4 d0 = __builtin_amdgcn_mfma_f32_16x16x32_bf16(at[6], bg, z4, 0, 0, 0);
      f32x4 d1 = __builtin_amdgcn_mfma_f32_16x16x32_bf16(at[7], bg, z4, 0, 0, 0);
      bf16x4 e0, e1;
#pragma unroll
      for (int r = 0; r < 4; ++r) {
        e0[r] = (short)f2bf(fexp2(fmaxf(d0[r], 0.f)));
        e1[r] = (short)f2bf(fexp2(fmaxf(d1[r], 0.f)));
      }
      *(bf16x4*)&En[rowm][SWC(96 + q * 4)] = e0;
      *(bf16x4*)&En[rowm][SWC(112 + q * 4)] = e1;
    }
    __syncthreads();  // buf p reads done; buf p^1 fully written & visible
  }

  // epilogue: lane holds col = (wc*3+c)*16 + q*4 + r, m = mb + wm*64 + ms*16 + i16
  float* pp = part + (size_t)blockIdx.y * 192 * NN;
#pragma unroll
  for (int c = 0; c < 3; ++c)
#pragma unroll
    for (int ms = 0; ms < 4; ++ms) {
      const int colbase = (wc * 3 + c) * 16 + q * 4;
      const int m = mb + wm * 64 + ms * 16 + i16;
#pragma unroll
      for (int r = 0; r < 4; ++r)
        pp[(size_t)(colbase + r) * NN + m] = acc[c][ms][r];
    }
}

// ---- reduce NSPLIT partials + transpose to out[bc][m][t] ----
__global__ __launch_bounds__(256) void k_reduce(const float* __restrict__ part,
                                                float* __restrict__ out) {
  __shared__ float os[3072];
  const int tid = threadIdx.x;
  const int m0 = blockIdx.x * 256;
  const int bc = blockIdx.y;
#pragma unroll
  for (int t = 0; t < 12; ++t) {
    const int col = bc * TT + t;
    float s = 0.f;
#pragma unroll
    for (int nc = 0; nc < NSPLIT; ++nc)
      s += part[((size_t)nc * 192 + col) * NN + m0 + tid];
    os[tid * 12 + t] = s;
  }
  __syncthreads();
  float* op = out + (size_t)bc * NN * TT + (size_t)m0 * TT;
#pragma unroll
  for (int j = 0; j < 12; ++j) op[j * 256 + tid] = os[j * 256 + tid];
}

extern "C" void kernel_launch(void* const* d_in, const int* in_sizes, int n_in,
                              void* d_out, int out_size, void* d_ws, size_t ws_size,
                              hipStream_t stream) {
  const float* x = (const float*)d_in[0];
  const float* nv1 = (const float*)d_in[1];
  const float* nv2 = (const float*)d_in[2];
  const float* tv = (const float*)d_in[3];
  const float* kk = (const float*)d_in[4];
  const int* tind = (const int*)d_in[5];
  float* out = (float*)d_out;

  char* ws = (char*)d_ws;
  unsigned short* t1b  = (unsigned short*)(ws);            //  524288 B
  unsigned short* nv2b = (unsigned short*)(ws + 524288);   //  524288 B
  float* sums          = (float*)(ws + 1048576);           //   32768 B
  unsigned short* yT   = (unsigned short*)(ws + 1081344);  // 3145728 B -> 4227072
  float* part          = (float*)(ws + 4227072);           // 50331648 B -> 54558720

  k_prep<<<64, 256, 0, stream>>>(nv1, nv2, tv, kk, tind, t1b, nv2b, sums);
  k_stats<<<dim3(128, 8), 256, 0, stream>>>(t1b, nv2b, sums);
  k_y<<<dim3(32, 16), 256, 0, stream>>>(x, sums, yT);
  k_mega<<<dim3(64, NSPLIT), 512, 0, stream>>>(t1b, nv2b, yT, part);
  k_reduce<<<dim3(32, 16), 256, 0, stream>>>(part, out);
}